// Round 8
// baseline (277.793 us; speedup 1.0000x reference)
//
#include <hip/hip_runtime.h>
#include <hip/hip_bf16.h>
#include <math.h>
#include <stdint.h>

#define DIM   64
#define KNB   16
#define QKVW  192

typedef short bf16x8 __attribute__((ext_vector_type(8)));
typedef float f32x4  __attribute__((ext_vector_type(4)));

__device__ __forceinline__ short f2bf_s(float x) {
    return (short)__builtin_bit_cast(unsigned short, __float2bfloat16(x));
}
__device__ __forceinline__ float bf2f(uint16_t u) {
    uint32_t v = ((uint32_t)u) << 16;
    return __builtin_bit_cast(float, v);
}

// ---------------------------------------------------------------------------
// prep: qkv projection (blocks < nqkvb) + weight prepack (remaining blocks).
// qkv -> bf16 [N][192] (q|k|v). Pack fragment: non-K = lane&15, K = 32kt+8(lane>>4)+j.
// ---------------------------------------------------------------------------
__global__ __launch_bounds__(256) void prep_kernel(
    const float* __restrict__ x, const float* __restrict__ wqkv,
    const float* __restrict__ am_w1, const float* __restrict__ am_w2,
    const float* __restrict__ pm_w2,
    uint16_t* __restrict__ qkvp, uint16_t* __restrict__ w1p,
    uint16_t* __restrict__ w2p, uint16_t* __restrict__ pw2p,
    int n, int nqkvb)
{
    const int tid = threadIdx.x;
    if (blockIdx.x < nqkvb) {
        const int c  = tid & 63;
        const int rq = tid >> 6;
        const int r0 = blockIdx.x * 16;
        __shared__ float s_x[16][64];
#pragma unroll
        for (int t = 0; t < 4; ++t) {
            const int row = r0 + rq + 4 * t;
            s_x[rq + 4 * t][c] = (row < n) ? x[(size_t)row * 64 + c] : 0.f;
        }
        __syncthreads();
        float aq[4] = {0, 0, 0, 0}, ak[4] = {0, 0, 0, 0}, av[4] = {0, 0, 0, 0};
        for (int d = 0; d < 64; ++d) {
            const float w0 = wqkv[d * QKVW + c];
            const float w1 = wqkv[d * QKVW + 64 + c];
            const float w2 = wqkv[d * QKVW + 128 + c];
#pragma unroll
            for (int t = 0; t < 4; ++t) {
                const float xv = s_x[rq + 4 * t][d];
                aq[t] = fmaf(xv, w0, aq[t]);
                ak[t] = fmaf(xv, w1, ak[t]);
                av[t] = fmaf(xv, w2, av[t]);
            }
        }
#pragma unroll
        for (int t = 0; t < 4; ++t) {
            const int row = r0 + rq + 4 * t;
            if (row < n) {
                qkvp[(size_t)row * QKVW + c]       = (uint16_t)f2bf_s(aq[t]);
                qkvp[(size_t)row * QKVW + 64 + c]  = (uint16_t)f2bf_s(ak[t]);
                qkvp[(size_t)row * QKVW + 128 + c] = (uint16_t)f2bf_s(av[t]);
            }
        }
    } else {
        int t = (blockIdx.x - nqkvb) * 256 + tid;
        if (t >= 36864) return;
        int j = t & 7, lane = (t >> 3) & 63, tile = t >> 9;
        int g = lane >> 4, nb = lane & 15;
        if (tile < 32) {
            int mt = tile >> 1, kt = tile & 1;
            w1p[t] = (uint16_t)f2bf_s(am_w1[(32 * kt + 8 * g + j) * 256 + 16 * mt + nb]);
        } else if (tile < 64) {
            int tt = tile - 32;
            int mt = tt >> 3, kt = tt & 7;
            w2p[t - 16384] = (uint16_t)f2bf_s(am_w2[(32 * kt + 8 * g + j) * 64 + 16 * mt + nb]);
        } else {
            int tt = tile - 64;
            int nt = tt >> 1, kt = tt & 1;
            pw2p[t - 32768] = (uint16_t)f2bf_s(pm_w2[(32 * kt + 8 * g + j) * 64 + 16 * nt + nb]);
        }
    }
}

// ---------------------------------------------------------------------------
// Main: 4 points/iteration, 4 waves, 2 barriers per 4 points, with T14-style
// register prefetch: next group's aidx / neighbor-pos / k-fragments are issued
// at the top of P3, so their ~900cy gather chain hides under P3 + next P1.
// s_rel holds rel' = rel - q (q folded at P1); P2 t-build is just k + rel'.
// ---------------------------------------------------------------------------
__global__ __launch_bounds__(256, 2) void ptl_main(
    const float* __restrict__ pos,
    const int* __restrict__ aidx,
    const uint8_t* __restrict__ mask,
    const float* __restrict__ pm_w1,
    const float* __restrict__ pm_b1,
    const float* __restrict__ pm_b2,
    const float* __restrict__ am_b1,
    const uint16_t* __restrict__ qkvp,
    const uint16_t* __restrict__ w1p,
    const uint16_t* __restrict__ w2p,
    const uint16_t* __restrict__ pw2p,
    float* __restrict__ out,
    int npts)
{
    const int tid  = threadIdx.x;
    const int w    = tid >> 6;
    const int lane = tid & 63;
    const int g    = lane >> 4;
    const int nb   = lane & 15;

    __shared__ alignas(16) uint16_t s_rel[4][16][80];   // rel' = rel - q (bf16)
    __shared__ alignas(16) uint16_t s_vrel[64][80];     // v + rel
    __shared__ alignas(16) uint16_t s_h2[64][256];      // slot-XOR swizzled

    // register-resident weights (64 VGPR)
    bf16x8 aw1[4][2], aw2[8];
#pragma unroll
    for (int m = 0; m < 4; ++m)
#pragma unroll
        for (int kt = 0; kt < 2; ++kt)
            aw1[m][kt] = *(const bf16x8*)(w1p + (size_t)(((4 * w + m) * 2 + kt) * 64 + lane) * 8);
#pragma unroll
    for (int kt = 0; kt < 8; ++kt)
        aw2[kt] = *(const bf16x8*)(w2p + (size_t)((w * 8 + kt) * 64 + lane) * 8);

    const int ngroups = (npts + 3) >> 2;

    // ---- prefetch registers (overwritten each iteration in P3) ----
    int pn0, pn1, pn2, pn3, pnw;
    float cx, cy, cz, prx, pry, prz;
    bf16x8 pk00, pk01, pk10, pk11, pk20, pk21, pk30, pk31;

    auto do_prefetch = [&](int gbn) {
        const int gcl = min(gbn, ngroups - 1);
        const int j0  = gcl * 4;
        const int jw  = min(j0 + w, npts - 1);
        pn0 = aidx[min(j0 + 0, npts - 1) * KNB + nb];
        pn1 = aidx[min(j0 + 1, npts - 1) * KNB + nb];
        pn2 = aidx[min(j0 + 2, npts - 1) * KNB + nb];
        pn3 = aidx[min(j0 + 3, npts - 1) * KNB + nb];
        pnw = aidx[jw * KNB + nb];
        cx = pos[3 * jw]; cy = pos[3 * jw + 1]; cz = pos[3 * jw + 2];
        prx = pos[3 * pnw]; pry = pos[3 * pnw + 1]; prz = pos[3 * pnw + 2];
        pk00 = *(const bf16x8*)(qkvp + (size_t)pn0 * QKVW + 64 + 8 * g);
        pk01 = *(const bf16x8*)(qkvp + (size_t)pn0 * QKVW + 96 + 8 * g);
        pk10 = *(const bf16x8*)(qkvp + (size_t)pn1 * QKVW + 64 + 8 * g);
        pk11 = *(const bf16x8*)(qkvp + (size_t)pn1 * QKVW + 96 + 8 * g);
        pk20 = *(const bf16x8*)(qkvp + (size_t)pn2 * QKVW + 64 + 8 * g);
        pk21 = *(const bf16x8*)(qkvp + (size_t)pn2 * QKVW + 96 + 8 * g);
        pk30 = *(const bf16x8*)(qkvp + (size_t)pn3 * QKVW + 64 + 8 * g);
        pk31 = *(const bf16x8*)(qkvp + (size_t)pn3 * QKVW + 96 + 8 * g);
    };

    do_prefetch(blockIdx.x);

    for (int gb = blockIdx.x; gb < ngroups; gb += gridDim.x) {
        const int i0 = gb * 4;

        // ================= P1: rel' for point i0+w =================
        {
            const int ipw = min(i0 + w, npts - 1);
            const float rx = prx - cx, ry = pry - cy, rz = prz - cz;

            bf16x8 h1f[2];
#pragma unroll
            for (int kt = 0; kt < 2; ++kt) {
                const int hb = 32 * kt + 8 * g;
                float w0[8], w1r[8], w2r[8], bb[8];
                *(float4*)&w0[0]  = *(const float4*)(pm_w1 + hb);
                *(float4*)&w0[4]  = *(const float4*)(pm_w1 + hb + 4);
                *(float4*)&w1r[0] = *(const float4*)(pm_w1 + 64 + hb);
                *(float4*)&w1r[4] = *(const float4*)(pm_w1 + 64 + hb + 4);
                *(float4*)&w2r[0] = *(const float4*)(pm_w1 + 128 + hb);
                *(float4*)&w2r[4] = *(const float4*)(pm_w1 + 128 + hb + 4);
                *(float4*)&bb[0]  = *(const float4*)(pm_b1 + hb);
                *(float4*)&bb[4]  = *(const float4*)(pm_b1 + hb + 4);
                bf16x8 f;
#pragma unroll
                for (int jj = 0; jj < 8; ++jj) {
                    float v = fmaf(rx, w0[jj], fmaf(ry, w1r[jj], fmaf(rz, w2r[jj], bb[jj])));
                    f[jj] = f2bf_s(fmaxf(v, 0.f));
                }
                h1f[kt] = f;
            }
#pragma unroll
            for (int nt = 0; nt < 4; ++nt) {
                const bf16x8 b0 = *(const bf16x8*)(pw2p + (size_t)((nt * 2 + 0) * 64 + lane) * 8);
                const bf16x8 b1 = *(const bf16x8*)(pw2p + (size_t)((nt * 2 + 1) * 64 + lane) * 8);
                f32x4 acc = {0.f, 0.f, 0.f, 0.f};
                acc = __builtin_amdgcn_mfma_f32_16x16x32_bf16(h1f[0], b0, acc, 0, 0, 0);
                acc = __builtin_amdgcn_mfma_f32_16x16x32_bf16(h1f[1], b1, acc, 0, 0, 0);
                const int ch = 16 * nt + nb;
                const float bias = pm_b2[ch];
                const float qv = bf2f(qkvp[(size_t)ipw * QKVW + ch]);   // fold -q here
#pragma unroll
                for (int r = 0; r < 4; ++r)
                    s_rel[w][4 * g + r][ch] = (uint16_t)f2bf_s(acc[r] + bias - qv);
            }
        }
        __syncthreads();

        // ================= P2: h2 stripe for all 64 pairs =================
#define P2_PT(PT, PKA, PKB, PN)                                                      \
        {                                                                             \
            const int ip = min(i0 + PT, npts - 1);                                    \
            const bf16x8 r8a = *(const bf16x8*)&s_rel[PT][nb][8 * g];                 \
            const bf16x8 r8b = *(const bf16x8*)&s_rel[PT][nb][32 + 8 * g];            \
            bf16x8 tf0, tf1;                                                          \
            _Pragma("unroll")                                                         \
            for (int jj = 0; jj < 8; ++jj) {                                          \
                tf0[jj] = f2bf_s(bf2f((uint16_t)PKA[jj]) + bf2f((uint16_t)r8a[jj]));  \
                tf1[jj] = f2bf_s(bf2f((uint16_t)PKB[jj]) + bf2f((uint16_t)r8b[jj]));  \
            }                                                                         \
            if (w == PT) {                                                            \
                const bf16x8 v8a = *(const bf16x8*)(qkvp + (size_t)PN * QKVW + 128 + 8 * g);  \
                const bf16x8 v8b = *(const bf16x8*)(qkvp + (size_t)PN * QKVW + 160 + 8 * g);  \
                const bf16x8 q8a = *(const bf16x8*)(qkvp + (size_t)ip * QKVW + 8 * g);        \
                const bf16x8 q8b = *(const bf16x8*)(qkvp + (size_t)ip * QKVW + 32 + 8 * g);   \
                bf16x8 va, vb;                                                        \
                _Pragma("unroll")                                                     \
                for (int jj = 0; jj < 8; ++jj) {                                      \
                    va[jj] = f2bf_s(bf2f((uint16_t)v8a[jj]) + bf2f((uint16_t)r8a[jj]) + bf2f((uint16_t)q8a[jj])); \
                    vb[jj] = f2bf_s(bf2f((uint16_t)v8b[jj]) + bf2f((uint16_t)r8b[jj]) + bf2f((uint16_t)q8b[jj])); \
                }                                                                     \
                *(bf16x8*)&s_vrel[16 * PT + nb][8 * g]      = va;                     \
                *(bf16x8*)&s_vrel[16 * PT + nb][32 + 8 * g] = vb;                     \
            }                                                                         \
            f32x4 hacc[4];                                                            \
            _Pragma("unroll")                                                         \
            for (int m = 0; m < 4; ++m) {                                             \
                f32x4 a = {0.f, 0.f, 0.f, 0.f};                                       \
                a = __builtin_amdgcn_mfma_f32_16x16x32_bf16(aw1[m][0], tf0, a, 0, 0, 0); \
                a = __builtin_amdgcn_mfma_f32_16x16x32_bf16(aw1[m][1], tf1, a, 0, 0, 0); \
                hacc[m] = a;                                                          \
            }                                                                         \
            _Pragma("unroll")                                                         \
            for (int m = 0; m < 4; ++m) {                                             \
                const int hb = 16 * (4 * w + m) + 4 * g;                              \
                const float4 b4 = *(const float4*)(am_b1 + hb);                       \
                const uint32_t lo = (uint32_t)(uint16_t)f2bf_s(fmaxf(hacc[m][0] + b4.x, 0.f))  \
                                  | ((uint32_t)(uint16_t)f2bf_s(fmaxf(hacc[m][1] + b4.y, 0.f)) << 16); \
                const uint32_t hi = (uint32_t)(uint16_t)f2bf_s(fmaxf(hacc[m][2] + b4.z, 0.f))  \
                                  | ((uint32_t)(uint16_t)f2bf_s(fmaxf(hacc[m][3] + b4.w, 0.f)) << 16); \
                const int sl = (2 * (4 * w + m) + (g >> 1)) ^ (nb & 7);               \
                *(uint2*)((char*)&s_h2[16 * PT + nb][0] + sl * 16 + 8 * (g & 1)) = make_uint2(lo, hi); \
            }                                                                         \
        }

        P2_PT(0, pk00, pk01, pn0)
        P2_PT(1, pk10, pk11, pn1)
        P2_PT(2, pk20, pk21, pn2)
        P2_PT(3, pk30, pk31, pn3)
#undef P2_PT
        __syncthreads();

        // ================= P3: prefetch next group, then scores+softmax+agg ====
        do_prefetch(gb + gridDim.x);

#pragma unroll
        for (int mt = 0; mt < 4; ++mt) {
            const int ip  = i0 + mt;
            const int ipc = min(ip, npts - 1);

            f32x4 wacc = {0.f, 0.f, 0.f, 0.f};
#pragma unroll
            for (int kt = 0; kt < 8; ++kt) {
                const int sl = (4 * kt + g) ^ (nb & 7);
                const bf16x8 a = *(const bf16x8*)((const char*)&s_h2[16 * mt + nb][0] + sl * 16);
                wacc = __builtin_amdgcn_mfma_f32_16x16x32_bf16(a, aw2[kt], wacc, 0, 0, 0);
            }

            const uchar4 m4 = *(const uchar4*)(mask + (size_t)ipc * KNB + 4 * g);
            const float sc0 = m4.x ? -INFINITY : wacc[0];
            const float sc1 = m4.y ? -INFINITY : wacc[1];
            const float sc2 = m4.z ? -INFINITY : wacc[2];
            const float sc3 = m4.w ? -INFINITY : wacc[3];
            float mx = fmaxf(fmaxf(sc0, sc1), fmaxf(sc2, sc3));
            mx = fmaxf(mx, __shfl_xor(mx, 16));
            mx = fmaxf(mx, __shfl_xor(mx, 32));
            const float e0 = __expf(sc0 - mx), e1 = __expf(sc1 - mx);
            const float e2 = __expf(sc2 - mx), e3 = __expf(sc3 - mx);
            float den = (e0 + e1) + (e2 + e3);

            const int vc = 16 * w + nb;
            const float vr0 = bf2f(s_vrel[16 * mt + 4 * g + 0][vc]);
            const float vr1 = bf2f(s_vrel[16 * mt + 4 * g + 1][vc]);
            const float vr2 = bf2f(s_vrel[16 * mt + 4 * g + 2][vc]);
            const float vr3 = bf2f(s_vrel[16 * mt + 4 * g + 3][vc]);
            float num = e0 * vr0;
            num = fmaf(e1, vr1, num);
            num = fmaf(e2, vr2, num);
            num = fmaf(e3, vr3, num);

            den += __shfl_xor(den, 16); den += __shfl_xor(den, 32);
            num += __shfl_xor(num, 16); num += __shfl_xor(num, 32);
            if (lane < 16 && ip < npts)
                out[(size_t)ip * 64 + vc] = __fdividef(num, den);
        }
        // no third barrier needed: P1' writes only s_rel (not read by P3);
        // P2' writes are behind barrier-1'.
    }
}

// ---------------------------------------------------------------------------
extern "C" void kernel_launch(void* const* d_in, const int* in_sizes, int n_in,
                              void* d_out, int out_size, void* d_ws, size_t ws_size,
                              hipStream_t stream) {
    const float*   x     = (const float*)d_in[0];
    const float*   pos   = (const float*)d_in[1];
    const int*     aidx  = (const int*)d_in[2];
    const uint8_t* mask  = (const uint8_t*)d_in[3];
    const float*   wqkv  = (const float*)d_in[4];
    const float*   pm_w1 = (const float*)d_in[5];
    const float*   pm_b1 = (const float*)d_in[6];
    const float*   pm_w2 = (const float*)d_in[7];
    const float*   pm_b2 = (const float*)d_in[8];
    const float*   am_w1 = (const float*)d_in[9];
    const float*   am_b1 = (const float*)d_in[10];
    const float*   am_w2 = (const float*)d_in[11];
    // am_b2 (d_in[12]) is constant over the softmax axis -> cancels, unused
    float* out = (float*)d_out;
    const int n = in_sizes[0] / DIM;

    uint8_t* ws = (uint8_t*)d_ws;
    uint16_t* qkvp = (uint16_t*)ws;                               // n*192 bf16
    uint16_t* w1p  = (uint16_t*)(ws + (size_t)n * QKVW * 2);      // 16384 bf16
    uint16_t* w2p  = w1p + 16384;                                 // 16384 bf16
    uint16_t* pw2p = w2p + 16384;                                 // 4096 bf16

    const int nqkvb = (n + 15) / 16;
    prep_kernel<<<nqkvb + 144, 256, 0, stream>>>(x, wqkv, am_w1, am_w2, pm_w2,
                                                 qkvp, w1p, w2p, pw2p, n, nqkvb);
    ptl_main<<<1024, 256, 0, stream>>>(pos, aidx, mask, pm_w1, pm_b1, pm_b2, am_b1,
                                       qkvp, w1p, w2p, pw2p, out, n);
}

// Round 9
// 264.258 us; speedup vs baseline: 1.0512x; 1.0512x over previous
//
#include <hip/hip_runtime.h>
#include <hip/hip_bf16.h>
#include <math.h>
#include <stdint.h>

#define DIM   64
#define KNB   16
#define QKVW  192
#define RPAD  72    // row pad for s_rel/s_vrel: 144B rows, 16B-aligned, banks spread

typedef short bf16x8 __attribute__((ext_vector_type(8)));
typedef float f32x4  __attribute__((ext_vector_type(4)));

__device__ __forceinline__ short f2bf_s(float x) {
    return (short)__builtin_bit_cast(unsigned short, __float2bfloat16(x));
}
__device__ __forceinline__ float bf2f(uint16_t u) {
    uint32_t v = ((uint32_t)u) << 16;
    return __builtin_bit_cast(float, v);
}

// ---------------------------------------------------------------------------
// prep: qkv projection (blocks < nqkvb) + weight prepack (remaining blocks).
// qkv -> bf16 [N][192] (q|k|v). Pack fragment: non-K = lane&15, K = 32kt+8(lane>>4)+j.
// ---------------------------------------------------------------------------
__global__ __launch_bounds__(256) void prep_kernel(
    const float* __restrict__ x, const float* __restrict__ wqkv,
    const float* __restrict__ am_w1, const float* __restrict__ am_w2,
    const float* __restrict__ pm_w2,
    uint16_t* __restrict__ qkvp, uint16_t* __restrict__ w1p,
    uint16_t* __restrict__ w2p, uint16_t* __restrict__ pw2p,
    int n, int nqkvb)
{
    const int tid = threadIdx.x;
    if (blockIdx.x < nqkvb) {
        const int c  = tid & 63;
        const int rq = tid >> 6;
        const int r0 = blockIdx.x * 16;
        __shared__ float s_x[16][64];
#pragma unroll
        for (int t = 0; t < 4; ++t) {
            const int row = r0 + rq + 4 * t;
            s_x[rq + 4 * t][c] = (row < n) ? x[(size_t)row * 64 + c] : 0.f;
        }
        __syncthreads();
        float aq[4] = {0, 0, 0, 0}, ak[4] = {0, 0, 0, 0}, av[4] = {0, 0, 0, 0};
        for (int d = 0; d < 64; ++d) {
            const float w0 = wqkv[d * QKVW + c];
            const float w1 = wqkv[d * QKVW + 64 + c];
            const float w2 = wqkv[d * QKVW + 128 + c];
#pragma unroll
            for (int t = 0; t < 4; ++t) {
                const float xv = s_x[rq + 4 * t][d];
                aq[t] = fmaf(xv, w0, aq[t]);
                ak[t] = fmaf(xv, w1, ak[t]);
                av[t] = fmaf(xv, w2, av[t]);
            }
        }
#pragma unroll
        for (int t = 0; t < 4; ++t) {
            const int row = r0 + rq + 4 * t;
            if (row < n) {
                qkvp[(size_t)row * QKVW + c]       = (uint16_t)f2bf_s(aq[t]);
                qkvp[(size_t)row * QKVW + 64 + c]  = (uint16_t)f2bf_s(ak[t]);
                qkvp[(size_t)row * QKVW + 128 + c] = (uint16_t)f2bf_s(av[t]);
            }
        }
    } else {
        int t = (blockIdx.x - nqkvb) * 256 + tid;
        if (t >= 36864) return;
        int j = t & 7, lane = (t >> 3) & 63, tile = t >> 9;
        int g = lane >> 4, nb = lane & 15;
        if (tile < 32) {
            int mt = tile >> 1, kt = tile & 1;
            w1p[t] = (uint16_t)f2bf_s(am_w1[(32 * kt + 8 * g + j) * 256 + 16 * mt + nb]);
        } else if (tile < 64) {
            int tt = tile - 32;
            int mt = tt >> 3, kt = tt & 7;
            w2p[t - 16384] = (uint16_t)f2bf_s(am_w2[(32 * kt + 8 * g + j) * 64 + 16 * mt + nb]);
        } else {
            int tt = tile - 64;
            int nt = tt >> 1, kt = tt & 1;
            pw2p[t - 32768] = (uint16_t)f2bf_s(pm_w2[(32 * kt + 8 * g + j) * 64 + 16 * nt + nb]);
        }
    }
}

// ---------------------------------------------------------------------------
// Main: 2 points per block-iteration (LDS 25.6 KB -> 4 blocks/CU at VGPR=128),
// 4 waves, 2 barriers per 2 points.
//  P1: wave w -> rel' (= rel - q) of point i0+(w>>1), nt tiles {2(w&1),2(w&1)+1}
//  P2: wave w -> h2[32 pairs][hidden 64w..64w+63] (16 MFMA); wave (2pt+kt)
//      writes s_vrel[pt] slice kt (v + rel' + q)
//  P3: wave w -> scores[32 pairs][out 16w..16w+15] (16 MFMA) + softmax + agg
// No third barrier: P1' writes only s_rel (unread by P3); P2' writes are
// behind barrier-1'.
// ---------------------------------------------------------------------------
__global__ __launch_bounds__(256, 2) void ptl_main(
    const float* __restrict__ pos,
    const int* __restrict__ aidx,
    const uint8_t* __restrict__ mask,
    const float* __restrict__ pm_w1,
    const float* __restrict__ pm_b1,
    const float* __restrict__ pm_b2,
    const float* __restrict__ am_b1,
    const uint16_t* __restrict__ qkvp,
    const uint16_t* __restrict__ w1p,
    const uint16_t* __restrict__ w2p,
    const uint16_t* __restrict__ pw2p,
    float* __restrict__ out,
    int npts)
{
    const int tid  = threadIdx.x;
    const int w    = tid >> 6;
    const int lane = tid & 63;
    const int g    = lane >> 4;
    const int nb   = lane & 15;

    __shared__ alignas(16) uint16_t s_rel[2][16][RPAD];   // rel' = rel - q
    __shared__ alignas(16) uint16_t s_vrel[32][RPAD];     // v + rel
    __shared__ alignas(16) uint16_t s_h2[32][256];        // slot-XOR swizzled

    // register-resident weights (64 VGPR)
    bf16x8 aw1[4][2], aw2[8];
#pragma unroll
    for (int m = 0; m < 4; ++m)
#pragma unroll
        for (int kt = 0; kt < 2; ++kt)
            aw1[m][kt] = *(const bf16x8*)(w1p + (size_t)(((4 * w + m) * 2 + kt) * 64 + lane) * 8);
#pragma unroll
    for (int kt = 0; kt < 8; ++kt)
        aw2[kt] = *(const bf16x8*)(w2p + (size_t)((w * 8 + kt) * 64 + lane) * 8);

    const int myp  = w >> 1;        // which of the 2 points this wave helps in P1
    const int ntb  = 2 * (w & 1);   // P1 nt-tile base
    const int vkt  = w & 1;         // P2 vrel kt slice

    const int ngroups = (npts + 1) >> 1;
    for (int gb = blockIdx.x; gb < ngroups; gb += gridDim.x) {
        const int i0 = gb * 2;

        // ================= P1: rel' for point i0+myp, 2 nt tiles ============
        {
            const int ip   = min(i0 + myp, npts - 1);
            const int nidx = aidx[ip * KNB + nb];
            const float rx = pos[3 * nidx]     - pos[3 * ip];
            const float ry = pos[3 * nidx + 1] - pos[3 * ip + 1];
            const float rz = pos[3 * nidx + 2] - pos[3 * ip + 2];

            bf16x8 h1f[2];
#pragma unroll
            for (int kt = 0; kt < 2; ++kt) {
                const int hb = 32 * kt + 8 * g;
                float w0[8], w1r[8], w2r[8], bb[8];
                *(float4*)&w0[0]  = *(const float4*)(pm_w1 + hb);
                *(float4*)&w0[4]  = *(const float4*)(pm_w1 + hb + 4);
                *(float4*)&w1r[0] = *(const float4*)(pm_w1 + 64 + hb);
                *(float4*)&w1r[4] = *(const float4*)(pm_w1 + 64 + hb + 4);
                *(float4*)&w2r[0] = *(const float4*)(pm_w1 + 128 + hb);
                *(float4*)&w2r[4] = *(const float4*)(pm_w1 + 128 + hb + 4);
                *(float4*)&bb[0]  = *(const float4*)(pm_b1 + hb);
                *(float4*)&bb[4]  = *(const float4*)(pm_b1 + hb + 4);
                bf16x8 f;
#pragma unroll
                for (int jj = 0; jj < 8; ++jj) {
                    float v = fmaf(rx, w0[jj], fmaf(ry, w1r[jj], fmaf(rz, w2r[jj], bb[jj])));
                    f[jj] = f2bf_s(fmaxf(v, 0.f));
                }
                h1f[kt] = f;
            }
#pragma unroll
            for (int t = 0; t < 2; ++t) {
                const int nt = ntb + t;
                const bf16x8 b0 = *(const bf16x8*)(pw2p + (size_t)((nt * 2 + 0) * 64 + lane) * 8);
                const bf16x8 b1 = *(const bf16x8*)(pw2p + (size_t)((nt * 2 + 1) * 64 + lane) * 8);
                f32x4 acc = {0.f, 0.f, 0.f, 0.f};
                acc = __builtin_amdgcn_mfma_f32_16x16x32_bf16(h1f[0], b0, acc, 0, 0, 0);
                acc = __builtin_amdgcn_mfma_f32_16x16x32_bf16(h1f[1], b1, acc, 0, 0, 0);
                const int ch = 16 * nt + nb;
                const float bias = pm_b2[ch];
                const float qv = bf2f(qkvp[(size_t)ip * QKVW + ch]);   // fold -q
#pragma unroll
                for (int r = 0; r < 4; ++r)
                    s_rel[myp][4 * g + r][ch] = (uint16_t)f2bf_s(acc[r] + bias - qv);
            }
        }
        __syncthreads();

        // ================= P2: h2 stripe for all 32 pairs ===================
        {
            bf16x8 tf[2][2];
#pragma unroll
            for (int pt = 0; pt < 2; ++pt) {
                const int ip   = min(i0 + pt, npts - 1);
                const int nidx = aidx[ip * KNB + nb];
                const uint16_t* kvr = qkvp + (size_t)nidx * QKVW;
#pragma unroll
                for (int kt = 0; kt < 2; ++kt) {
                    const int cb = 32 * kt + 8 * g;
                    const bf16x8 k8 = *(const bf16x8*)(kvr + 64 + cb);
                    const bf16x8 r8 = *(const bf16x8*)&s_rel[pt][nb][cb];
                    bf16x8 f;
#pragma unroll
                    for (int j = 0; j < 8; ++j)
                        f[j] = f2bf_s(bf2f((uint16_t)k8[j]) + bf2f((uint16_t)r8[j]));
                    tf[pt][kt] = f;
                    if (pt == myp && kt == vkt) {   // wave-uniform
                        const bf16x8 v8 = *(const bf16x8*)(kvr + 128 + cb);
                        const bf16x8 q8 = *(const bf16x8*)(qkvp + (size_t)ip * QKVW + cb);
                        bf16x8 vf;
#pragma unroll
                        for (int j = 0; j < 8; ++j)
                            vf[j] = f2bf_s(bf2f((uint16_t)v8[j]) + bf2f((uint16_t)r8[j])
                                           + bf2f((uint16_t)q8[j]));
                        *(bf16x8*)&s_vrel[16 * pt + nb][cb] = vf;
                    }
                }
            }

            f32x4 hacc[4][2];
#pragma unroll
            for (int m = 0; m < 4; ++m)
#pragma unroll
                for (int pt = 0; pt < 2; ++pt) {
                    f32x4 a = {0.f, 0.f, 0.f, 0.f};
                    a = __builtin_amdgcn_mfma_f32_16x16x32_bf16(aw1[m][0], tf[pt][0], a, 0, 0, 0);
                    a = __builtin_amdgcn_mfma_f32_16x16x32_bf16(aw1[m][1], tf[pt][1], a, 0, 0, 0);
                    hacc[m][pt] = a;
                }
#pragma unroll
            for (int m = 0; m < 4; ++m) {
                const int hb = 16 * (4 * w + m) + 4 * g;
                const float4 b4 = *(const float4*)(am_b1 + hb);
                const int sl = (2 * (4 * w + m) + (g >> 1)) ^ (nb & 7);
#pragma unroll
                for (int pt = 0; pt < 2; ++pt) {
                    const uint32_t lo = (uint32_t)(uint16_t)f2bf_s(fmaxf(hacc[m][pt][0] + b4.x, 0.f))
                                      | ((uint32_t)(uint16_t)f2bf_s(fmaxf(hacc[m][pt][1] + b4.y, 0.f)) << 16);
                    const uint32_t hi = (uint32_t)(uint16_t)f2bf_s(fmaxf(hacc[m][pt][2] + b4.z, 0.f))
                                      | ((uint32_t)(uint16_t)f2bf_s(fmaxf(hacc[m][pt][3] + b4.w, 0.f)) << 16);
                    *(uint2*)((char*)&s_h2[16 * pt + nb][0] + sl * 16 + 8 * (g & 1)) = make_uint2(lo, hi);
                }
            }
        }
        __syncthreads();

        // ================= P3: scores + softmax + agg, per point pt =========
#pragma unroll
        for (int pt = 0; pt < 2; ++pt) {
            const int ip  = i0 + pt;
            const int ipc = min(ip, npts - 1);

            f32x4 wacc = {0.f, 0.f, 0.f, 0.f};
#pragma unroll
            for (int kt = 0; kt < 8; ++kt) {
                const int sl = (4 * kt + g) ^ (nb & 7);
                const bf16x8 a = *(const bf16x8*)((const char*)&s_h2[16 * pt + nb][0] + sl * 16);
                wacc = __builtin_amdgcn_mfma_f32_16x16x32_bf16(a, aw2[kt], wacc, 0, 0, 0);
            }

            const uchar4 m4 = *(const uchar4*)(mask + (size_t)ipc * KNB + 4 * g);
            const float sc0 = m4.x ? -INFINITY : wacc[0];
            const float sc1 = m4.y ? -INFINITY : wacc[1];
            const float sc2 = m4.z ? -INFINITY : wacc[2];
            const float sc3 = m4.w ? -INFINITY : wacc[3];
            float mx = fmaxf(fmaxf(sc0, sc1), fmaxf(sc2, sc3));
            mx = fmaxf(mx, __shfl_xor(mx, 16));
            mx = fmaxf(mx, __shfl_xor(mx, 32));
            const float e0 = __expf(sc0 - mx), e1 = __expf(sc1 - mx);
            const float e2 = __expf(sc2 - mx), e3 = __expf(sc3 - mx);
            float den = (e0 + e1) + (e2 + e3);

            const int vc = 16 * w + nb;
            const float vr0 = bf2f(s_vrel[16 * pt + 4 * g + 0][vc]);
            const float vr1 = bf2f(s_vrel[16 * pt + 4 * g + 1][vc]);
            const float vr2 = bf2f(s_vrel[16 * pt + 4 * g + 2][vc]);
            const float vr3 = bf2f(s_vrel[16 * pt + 4 * g + 3][vc]);
            float num = e0 * vr0;
            num = fmaf(e1, vr1, num);
            num = fmaf(e2, vr2, num);
            num = fmaf(e3, vr3, num);

            den += __shfl_xor(den, 16); den += __shfl_xor(den, 32);
            num += __shfl_xor(num, 16); num += __shfl_xor(num, 32);
            if (lane < 16 && ip < npts)
                out[(size_t)ip * 64 + vc] = __fdividef(num, den);
        }
        // no third barrier needed (see header comment)
    }
}

// ---------------------------------------------------------------------------
extern "C" void kernel_launch(void* const* d_in, const int* in_sizes, int n_in,
                              void* d_out, int out_size, void* d_ws, size_t ws_size,
                              hipStream_t stream) {
    const float*   x     = (const float*)d_in[0];
    const float*   pos   = (const float*)d_in[1];
    const int*     aidx  = (const int*)d_in[2];
    const uint8_t* mask  = (const uint8_t*)d_in[3];
    const float*   wqkv  = (const float*)d_in[4];
    const float*   pm_w1 = (const float*)d_in[5];
    const float*   pm_b1 = (const float*)d_in[6];
    const float*   pm_w2 = (const float*)d_in[7];
    const float*   pm_b2 = (const float*)d_in[8];
    const float*   am_w1 = (const float*)d_in[9];
    const float*   am_b1 = (const float*)d_in[10];
    const float*   am_w2 = (const float*)d_in[11];
    // am_b2 (d_in[12]) is constant over the softmax axis -> cancels, unused
    float* out = (float*)d_out;
    const int n = in_sizes[0] / DIM;

    uint8_t* ws = (uint8_t*)d_ws;
    uint16_t* qkvp = (uint16_t*)ws;                               // n*192 bf16
    uint16_t* w1p  = (uint16_t*)(ws + (size_t)n * QKVW * 2);      // 16384 bf16
    uint16_t* w2p  = w1p + 16384;                                 // 16384 bf16
    uint16_t* pw2p = w2p + 16384;                                 // 4096 bf16

    const int nqkvb = (n + 15) / 16;
    prep_kernel<<<nqkvb + 144, 256, 0, stream>>>(x, wqkv, am_w1, am_w2, pm_w2,
                                                 qkvp, w1p, w2p, pw2p, n, nqkvb);
    ptl_main<<<2048, 256, 0, stream>>>(pos, aidx, mask, pm_w1, pm_b1, pm_b2, am_b1,
                                       qkvp, w1p, w2p, pw2p, out, n);
}

// Round 10
// 255.886 us; speedup vs baseline: 1.0856x; 1.0327x over previous
//
#include <hip/hip_runtime.h>
#include <hip/hip_bf16.h>
#include <math.h>
#include <stdint.h>

#define DIM   64
#define KNB   16
#define QKVW  192
#define XWW   576   // per-row: KW1(256) | QW1b(256) | v(64)
#define RPAD  72
#define H2PAD 272   // fallback layout
#define KVPAD 144

typedef short bf16x8 __attribute__((ext_vector_type(8)));
typedef float f32x4  __attribute__((ext_vector_type(4)));

__device__ __forceinline__ short f2bf_s(float x) {
    return (short)__builtin_bit_cast(unsigned short, __float2bfloat16(x));
}
__device__ __forceinline__ float bf2f(uint16_t u) {
    uint32_t v = ((uint32_t)u) << 16;
    return __builtin_bit_cast(float, v);
}

// ===========================================================================
// NEW PATH
// ===========================================================================

// ---------------------------------------------------------------------------
// pack: small fused-weight matrices + MFMA fragment packs, all inline dots.
//  whbp: B-frags of W_cat[64,576] = [wqkv_k@am_w1 | wqkv_q@am_w1 | wqkv_v]
//  wprp: A-frags of (pm_w2@am_w1)^T   (M=256 hidden-out, K=64 pos-hidden)
//  w2p : A-frags of am_w2^T           (M=64 out, K=256)
//  pw2p: B-frags of pm_w2             (K=64, N=64)
//  bp  : b' = pm_b2@am_w1 + am_b1     (f32[256])
// Fragment: non-K = lane&15, K = 32*kt + 8*(lane>>4) + j.
// ---------------------------------------------------------------------------
__global__ __launch_bounds__(256) void pack_kernel(
    const float* __restrict__ wqkv, const float* __restrict__ am_w1,
    const float* __restrict__ am_w2, const float* __restrict__ pm_w2,
    const float* __restrict__ pm_b2, const float* __restrict__ am_b1,
    uint16_t* __restrict__ whbp, uint16_t* __restrict__ wprp,
    uint16_t* __restrict__ w2p, uint16_t* __restrict__ pw2p,
    float* __restrict__ bp)
{
    const int t = blockIdx.x * 256 + threadIdx.x;
    if (t < 36864) {                       // whbp: 36 nt x 2 kt x 512
        const int j = t & 7, lane = (t >> 3) & 63, tile = t >> 9;
        const int g = lane >> 4, nb = lane & 15;
        const int nt = tile >> 1, kt = tile & 1;
        const int k = 32 * kt + 8 * g + j;
        const int col = 16 * nt + nb;
        float v;
        if (col < 256) {
            v = 0.f;
            for (int e = 0; e < 64; ++e)
                v = fmaf(wqkv[k * QKVW + 64 + e], am_w1[e * 256 + col], v);
        } else if (col < 512) {
            v = 0.f;
            for (int e = 0; e < 64; ++e)
                v = fmaf(wqkv[k * QKVW + e], am_w1[e * 256 + (col - 256)], v);
        } else {
            v = wqkv[k * QKVW + 128 + (col - 512)];
        }
        whbp[t] = (uint16_t)f2bf_s(v);
    } else if (t < 53248) {                // wprp: 16 mt x 2 kt x 512
        const int t2 = t - 36864;
        const int j = t2 & 7, lane = (t2 >> 3) & 63, tile = t2 >> 9;
        const int g = lane >> 4, nb = lane & 15;
        const int mt = tile >> 1, kt = tile & 1;
        const int k = 32 * kt + 8 * g + j;
        const int col = 16 * mt + nb;
        float v = 0.f;
        for (int e = 0; e < 64; ++e)
            v = fmaf(pm_w2[k * 64 + e], am_w1[e * 256 + col], v);
        wprp[t2] = (uint16_t)f2bf_s(v);
    } else if (t < 69632) {                // w2p: 4 mt x 8 kt x 512
        const int t3 = t - 53248;
        const int j = t3 & 7, lane = (t3 >> 3) & 63, tile = t3 >> 9;
        const int g = lane >> 4, nb = lane & 15;
        const int mt = tile >> 3, kt = tile & 7;
        w2p[t3] = (uint16_t)f2bf_s(am_w2[(32 * kt + 8 * g + j) * 64 + 16 * mt + nb]);
    } else if (t < 73728) {                // pw2p: 4 nt x 2 kt x 512
        const int t4 = t - 69632;
        const int j = t4 & 7, lane = (t4 >> 3) & 63, tile = t4 >> 9;
        const int g = lane >> 4, nb = lane & 15;
        const int nt = tile >> 1, kt = tile & 1;
        pw2p[t4] = (uint16_t)f2bf_s(pm_w2[(32 * kt + 8 * g + j) * 64 + 16 * nt + nb]);
    } else if (t < 73984) {                // bp
        const int c = t - 73728;
        float v = am_b1[c];
        for (int d = 0; d < 64; ++d)
            v = fmaf(pm_b2[d], am_w1[d * 256 + c], v);
        bp[c] = v;
    }
}

// ---------------------------------------------------------------------------
// xw: [N,64]@[64,576] MFMA GEMM -> xw[N][576] bf16 (KW1 | QW1b | v).
// 16 rows/block, wave w owns 9 col-tiles. b' subtracted for cols 256..511.
// ---------------------------------------------------------------------------
__global__ __launch_bounds__(256) void xw_kernel(
    const float* __restrict__ x, const uint16_t* __restrict__ whbp,
    const float* __restrict__ bp, uint16_t* __restrict__ xw, int n)
{
    const int tid = threadIdx.x;
    const int w4  = tid >> 6;
    const int lane = tid & 63;
    const int g = lane >> 4, nb = lane & 15;
    const int r0 = blockIdx.x * 16;
    const int rowA = min(r0 + nb, n - 1);

    bf16x8 af[2];
#pragma unroll
    for (int kt = 0; kt < 2; ++kt) {
        const float* xr = x + (size_t)rowA * 64 + 32 * kt + 8 * g;
        const float4 a0 = *(const float4*)xr;
        const float4 a1 = *(const float4*)(xr + 4);
        bf16x8 f;
        f[0] = f2bf_s(a0.x); f[1] = f2bf_s(a0.y); f[2] = f2bf_s(a0.z); f[3] = f2bf_s(a0.w);
        f[4] = f2bf_s(a1.x); f[5] = f2bf_s(a1.y); f[6] = f2bf_s(a1.z); f[7] = f2bf_s(a1.w);
        af[kt] = f;
    }

#pragma unroll
    for (int t = 0; t < 9; ++t) {
        const int nt = 9 * w4 + t;
        const bf16x8 b0 = *(const bf16x8*)(whbp + (size_t)((nt * 2 + 0) * 64 + lane) * 8);
        const bf16x8 b1 = *(const bf16x8*)(whbp + (size_t)((nt * 2 + 1) * 64 + lane) * 8);
        f32x4 acc = {0.f, 0.f, 0.f, 0.f};
        acc = __builtin_amdgcn_mfma_f32_16x16x32_bf16(af[0], b0, acc, 0, 0, 0);
        acc = __builtin_amdgcn_mfma_f32_16x16x32_bf16(af[1], b1, acc, 0, 0, 0);
        const int col = 16 * nt + nb;
        const float bs = (nt >= 16 && nt < 32) ? bp[col - 256] : 0.f;
#pragma unroll
        for (int r = 0; r < 4; ++r) {
            const int row = r0 + 4 * g + r;
            if (row < n)
                xw[(size_t)row * XWW + col] = (uint16_t)f2bf_s(acc[r] - bs);
        }
    }
}

// ---------------------------------------------------------------------------
// Main (new): 4 points/iter, 4 waves, 2 barriers per 4 points.
//  P1: wave w -> h1 frags of its point -> s_h1[w] (own-slot, zero-conv reuse);
//      rel = h1@pm_w2 + pm_b2 -> s_rel[w] (wave-private scratch).
//  P2: wave w -> h2 stripe: C-init = KW1[j] - QW1b[i] (8B gathers), then
//      2 MFMA with h1 frags from s_h1 -> relu -> s_h2. Owner builds vrel.
//  P3: scores + softmax + agg (as round 7).
// Race-free with 2 barriers: P3 reads only s_h2/s_vrel; next P1 writes only
// s_h1[w]/s_rel[w] (unread in P3); next P2 writes are behind its barrier.
// ---------------------------------------------------------------------------
__global__ __launch_bounds__(256, 2) void ptl_main(
    const float* __restrict__ pos,
    const int* __restrict__ aidx,
    const uint8_t* __restrict__ mask,
    const float* __restrict__ pm_w1,
    const float* __restrict__ pm_b1,
    const float* __restrict__ pm_b2,
    const uint16_t* __restrict__ xw,
    const uint16_t* __restrict__ wprp,
    const uint16_t* __restrict__ w2p,
    const uint16_t* __restrict__ pw2p,
    float* __restrict__ out,
    int npts)
{
    const int tid  = threadIdx.x;
    const int w    = tid >> 6;
    const int lane = tid & 63;
    const int g    = lane >> 4;
    const int nb   = lane & 15;

    __shared__ alignas(16) uint16_t s_h1[4][64][16];    // h1 frags, own-slot
    __shared__ alignas(16) uint16_t s_rel[4][16][RPAD]; // rel (wave-private)
    __shared__ alignas(16) uint16_t s_vrel[64][RPAD];   // v + rel
    __shared__ alignas(16) uint16_t s_h2[64][256];      // slot-XOR swizzled

    // register-resident weights (64 VGPR)
    bf16x8 wpr[4][2], aw2[8];
#pragma unroll
    for (int m = 0; m < 4; ++m)
#pragma unroll
        for (int kt = 0; kt < 2; ++kt)
            wpr[m][kt] = *(const bf16x8*)(wprp + (size_t)(((4 * w + m) * 2 + kt) * 64 + lane) * 8);
#pragma unroll
    for (int kt = 0; kt < 8; ++kt)
        aw2[kt] = *(const bf16x8*)(w2p + (size_t)((w * 8 + kt) * 64 + lane) * 8);

    const int ngroups = (npts + 3) >> 2;
    for (int gb = blockIdx.x; gb < ngroups; gb += gridDim.x) {
        const int i0 = gb * 4;
        int nidxp[4];
#pragma unroll
        for (int pt = 0; pt < 4; ++pt)
            nidxp[pt] = aidx[min(i0 + pt, npts - 1) * KNB + nb];

        // ================= P1 =================
        {
            const int ipw  = min(i0 + w, npts - 1);
            const int nidx = aidx[ipw * KNB + nb];   // avoid runtime-indexed array
            const float rx = pos[3 * nidx]     - pos[3 * ipw];
            const float ry = pos[3 * nidx + 1] - pos[3 * ipw + 1];
            const float rz = pos[3 * nidx + 2] - pos[3 * ipw + 2];

            bf16x8 h1f[2];
#pragma unroll
            for (int kt = 0; kt < 2; ++kt) {
                const int hb = 32 * kt + 8 * g;
                float w0[8], w1r[8], w2r[8], bb[8];
                *(float4*)&w0[0]  = *(const float4*)(pm_w1 + hb);
                *(float4*)&w0[4]  = *(const float4*)(pm_w1 + hb + 4);
                *(float4*)&w1r[0] = *(const float4*)(pm_w1 + 64 + hb);
                *(float4*)&w1r[4] = *(const float4*)(pm_w1 + 64 + hb + 4);
                *(float4*)&w2r[0] = *(const float4*)(pm_w1 + 128 + hb);
                *(float4*)&w2r[4] = *(const float4*)(pm_w1 + 128 + hb + 4);
                *(float4*)&bb[0]  = *(const float4*)(pm_b1 + hb);
                *(float4*)&bb[4]  = *(const float4*)(pm_b1 + hb + 4);
                bf16x8 f;
#pragma unroll
                for (int jj = 0; jj < 8; ++jj) {
                    float v = fmaf(rx, w0[jj], fmaf(ry, w1r[jj], fmaf(rz, w2r[jj], bb[jj])));
                    f[jj] = f2bf_s(fmaxf(v, 0.f));
                }
                h1f[kt] = f;
            }
            *(bf16x8*)&s_h1[w][lane][0] = h1f[0];
            *(bf16x8*)&s_h1[w][lane][8] = h1f[1];

#pragma unroll
            for (int nt = 0; nt < 4; ++nt) {
                const bf16x8 b0 = *(const bf16x8*)(pw2p + (size_t)((nt * 2 + 0) * 64 + lane) * 8);
                const bf16x8 b1 = *(const bf16x8*)(pw2p + (size_t)((nt * 2 + 1) * 64 + lane) * 8);
                f32x4 acc = {0.f, 0.f, 0.f, 0.f};
                acc = __builtin_amdgcn_mfma_f32_16x16x32_bf16(h1f[0], b0, acc, 0, 0, 0);
                acc = __builtin_amdgcn_mfma_f32_16x16x32_bf16(h1f[1], b1, acc, 0, 0, 0);
                const int ch = 16 * nt + nb;
                const float bias = pm_b2[ch];
#pragma unroll
                for (int r = 0; r < 4; ++r)
                    s_rel[w][4 * g + r][ch] = (uint16_t)f2bf_s(acc[r] + bias);
            }
        }
        __syncthreads();

        // ================= P2 =================
#pragma unroll
        for (int pt = 0; pt < 4; ++pt) {
            const int ip = min(i0 + pt, npts - 1);
            const bf16x8 tf0 = *(const bf16x8*)&s_h1[pt][lane][0];
            const bf16x8 tf1 = *(const bf16x8*)&s_h1[pt][lane][8];
            const size_t krow = (size_t)nidxp[pt] * XWW;
            const size_t qrow = (size_t)ip * XWW + 256;

            f32x4 hacc[4];
#pragma unroll
            for (int m = 0; m < 4; ++m) {
                const int hb = 16 * (4 * w + m) + 4 * g;
                const ushort4 kw = *(const ushort4*)(xw + krow + hb);
                const ushort4 qw = *(const ushort4*)(xw + qrow + hb);
                f32x4 c;
                c[0] = bf2f(kw.x) - bf2f(qw.x);
                c[1] = bf2f(kw.y) - bf2f(qw.y);
                c[2] = bf2f(kw.z) - bf2f(qw.z);
                c[3] = bf2f(kw.w) - bf2f(qw.w);
                c = __builtin_amdgcn_mfma_f32_16x16x32_bf16(wpr[m][0], tf0, c, 0, 0, 0);
                c = __builtin_amdgcn_mfma_f32_16x16x32_bf16(wpr[m][1], tf1, c, 0, 0, 0);
                hacc[m] = c;
            }

            if (pt == w) {   // wave-uniform: owner builds vrel = v + rel
#pragma unroll
                for (int kt = 0; kt < 2; ++kt) {
                    const int cb = 32 * kt + 8 * g;
                    const bf16x8 v8 = *(const bf16x8*)(xw + krow + 512 + cb);
                    const bf16x8 r8 = *(const bf16x8*)&s_rel[w][nb][cb];
                    bf16x8 vf;
#pragma unroll
                    for (int j = 0; j < 8; ++j)
                        vf[j] = f2bf_s(bf2f((uint16_t)v8[j]) + bf2f((uint16_t)r8[j]));
                    *(bf16x8*)&s_vrel[16 * w + nb][cb] = vf;
                }
            }

#pragma unroll
            for (int m = 0; m < 4; ++m) {
                const uint32_t lo = (uint32_t)(uint16_t)f2bf_s(fmaxf(hacc[m][0], 0.f))
                                  | ((uint32_t)(uint16_t)f2bf_s(fmaxf(hacc[m][1], 0.f)) << 16);
                const uint32_t hi = (uint32_t)(uint16_t)f2bf_s(fmaxf(hacc[m][2], 0.f))
                                  | ((uint32_t)(uint16_t)f2bf_s(fmaxf(hacc[m][3], 0.f)) << 16);
                const int sl = (2 * (4 * w + m) + (g >> 1)) ^ (nb & 7);
                *(uint2*)((char*)&s_h2[16 * pt + nb][0] + sl * 16 + 8 * (g & 1)) = make_uint2(lo, hi);
            }
        }
        __syncthreads();

        // ================= P3 =================
#pragma unroll
        for (int mt = 0; mt < 4; ++mt) {
            const int ip  = i0 + mt;
            const int ipc = min(ip, npts - 1);

            f32x4 wacc = {0.f, 0.f, 0.f, 0.f};
#pragma unroll
            for (int kt = 0; kt < 8; ++kt) {
                const int sl = (4 * kt + g) ^ (nb & 7);
                const bf16x8 a = *(const bf16x8*)((const char*)&s_h2[16 * mt + nb][0] + sl * 16);
                wacc = __builtin_amdgcn_mfma_f32_16x16x32_bf16(a, aw2[kt], wacc, 0, 0, 0);
            }

            const uchar4 m4 = *(const uchar4*)(mask + (size_t)ipc * KNB + 4 * g);
            const float sc0 = m4.x ? -INFINITY : wacc[0];
            const float sc1 = m4.y ? -INFINITY : wacc[1];
            const float sc2 = m4.z ? -INFINITY : wacc[2];
            const float sc3 = m4.w ? -INFINITY : wacc[3];
            float mx = fmaxf(fmaxf(sc0, sc1), fmaxf(sc2, sc3));
            mx = fmaxf(mx, __shfl_xor(mx, 16));
            mx = fmaxf(mx, __shfl_xor(mx, 32));
            const float e0 = __expf(sc0 - mx), e1 = __expf(sc1 - mx);
            const float e2 = __expf(sc2 - mx), e3 = __expf(sc3 - mx);
            float den = (e0 + e1) + (e2 + e3);

            const int vc = 16 * w + nb;
            const float vr0 = bf2f(s_vrel[16 * mt + 4 * g + 0][vc]);
            const float vr1 = bf2f(s_vrel[16 * mt + 4 * g + 1][vc]);
            const float vr2 = bf2f(s_vrel[16 * mt + 4 * g + 2][vc]);
            const float vr3 = bf2f(s_vrel[16 * mt + 4 * g + 3][vc]);
            float num = e0 * vr0;
            num = fmaf(e1, vr1, num);
            num = fmaf(e2, vr2, num);
            num = fmaf(e3, vr3, num);

            den += __shfl_xor(den, 16); den += __shfl_xor(den, 32);
            num += __shfl_xor(num, 16); num += __shfl_xor(num, 32);
            if (lane < 16 && ip < npts)
                out[(size_t)ip * 64 + vc] = __fdividef(num, den);
        }
    }
}

// ===========================================================================
// FALLBACK PATH (round-7, proven 218 us) — used when ws is too small
// ===========================================================================
__global__ __launch_bounds__(256) void prep_fb(
    const float* __restrict__ x, const float* __restrict__ wqkv,
    const float* __restrict__ am_w1, const float* __restrict__ am_w2,
    const float* __restrict__ pm_w2,
    uint16_t* __restrict__ qkvp, uint16_t* __restrict__ w1p,
    uint16_t* __restrict__ w2p, uint16_t* __restrict__ pw2p,
    int n, int nqkvb)
{
    const int tid = threadIdx.x;
    if (blockIdx.x < nqkvb) {
        const int c  = tid & 63;
        const int rq = tid >> 6;
        const int r0 = blockIdx.x * 16;
        __shared__ float s_x[16][64];
#pragma unroll
        for (int t = 0; t < 4; ++t) {
            const int row = r0 + rq + 4 * t;
            s_x[rq + 4 * t][c] = (row < n) ? x[(size_t)row * 64 + c] : 0.f;
        }
        __syncthreads();
        float aq[4] = {0, 0, 0, 0}, ak[4] = {0, 0, 0, 0}, av[4] = {0, 0, 0, 0};
        for (int d = 0; d < 64; ++d) {
            const float w0 = wqkv[d * QKVW + c];
            const float w1 = wqkv[d * QKVW + 64 + c];
            const float w2 = wqkv[d * QKVW + 128 + c];
#pragma unroll
            for (int t = 0; t < 4; ++t) {
                const float xv = s_x[rq + 4 * t][d];
                aq[t] = fmaf(xv, w0, aq[t]);
                ak[t] = fmaf(xv, w1, ak[t]);
                av[t] = fmaf(xv, w2, av[t]);
            }
        }
#pragma unroll
        for (int t = 0; t < 4; ++t) {
            const int row = r0 + rq + 4 * t;
            if (row < n) {
                qkvp[(size_t)row * QKVW + c]       = (uint16_t)f2bf_s(aq[t]);
                qkvp[(size_t)row * QKVW + 64 + c]  = (uint16_t)f2bf_s(ak[t]);
                qkvp[(size_t)row * QKVW + 128 + c] = (uint16_t)f2bf_s(av[t]);
            }
        }
    } else {
        int t = (blockIdx.x - nqkvb) * 256 + tid;
        if (t >= 36864) return;
        int j = t & 7, lane = (t >> 3) & 63, tile = t >> 9;
        int g = lane >> 4, nb = lane & 15;
        if (tile < 32) {
            int mt = tile >> 1, kt = tile & 1;
            w1p[t] = (uint16_t)f2bf_s(am_w1[(32 * kt + 8 * g + j) * 256 + 16 * mt + nb]);
        } else if (tile < 64) {
            int tt = tile - 32;
            int mt = tt >> 3, kt = tt & 7;
            w2p[t - 16384] = (uint16_t)f2bf_s(am_w2[(32 * kt + 8 * g + j) * 64 + 16 * mt + nb]);
        } else {
            int tt = tile - 64;
            int nt = tt >> 1, kt = tt & 1;
            pw2p[t - 32768] = (uint16_t)f2bf_s(pm_w2[(32 * kt + 8 * g + j) * 64 + 16 * nt + nb]);
        }
    }
}

__global__ __launch_bounds__(256, 2) void ptl_main_fb(
    const float* __restrict__ pos,
    const int* __restrict__ aidx,
    const uint8_t* __restrict__ mask,
    const float* __restrict__ pm_w1,
    const float* __restrict__ pm_b1,
    const float* __restrict__ pm_b2,
    const float* __restrict__ am_b1,
    const uint16_t* __restrict__ qkvp,
    const uint16_t* __restrict__ w1p,
    const uint16_t* __restrict__ w2p,
    const uint16_t* __restrict__ pw2p,
    float* __restrict__ out,
    int npts)
{
    const int tid  = threadIdx.x;
    const int w    = tid >> 6;
    const int lane = tid & 63;
    const int g    = lane >> 4;
    const int nb   = lane & 15;

    __shared__ alignas(16) uint16_t s_rel[4][16][80];
    __shared__ alignas(16) uint16_t s_vrel[64][80];
    __shared__ alignas(16) uint16_t s_h2[64][256];

    bf16x8 aw1[4][2], aw2[8];
#pragma unroll
    for (int m = 0; m < 4; ++m)
#pragma unroll
        for (int kt = 0; kt < 2; ++kt)
            aw1[m][kt] = *(const bf16x8*)(w1p + (size_t)(((4 * w + m) * 2 + kt) * 64 + lane) * 8);
#pragma unroll
    for (int kt = 0; kt < 8; ++kt)
        aw2[kt] = *(const bf16x8*)(w2p + (size_t)((w * 8 + kt) * 64 + lane) * 8);

    const int ngroups = (npts + 3) >> 2;
    for (int gb = blockIdx.x; gb < ngroups; gb += gridDim.x) {
        const int i0 = gb * 4;
        {
            const int ip   = min(i0 + w, npts - 1);
            const int nidx = aidx[ip * KNB + nb];
            const float rx = pos[3 * nidx]     - pos[3 * ip];
            const float ry = pos[3 * nidx + 1] - pos[3 * ip + 1];
            const float rz = pos[3 * nidx + 2] - pos[3 * ip + 2];

            bf16x8 h1f[2];
#pragma unroll
            for (int kt = 0; kt < 2; ++kt) {
                const int hb = 32 * kt + 8 * g;
                float w0[8], w1r[8], w2r[8], bb[8];
                *(float4*)&w0[0]  = *(const float4*)(pm_w1 + hb);
                *(float4*)&w0[4]  = *(const float4*)(pm_w1 + hb + 4);
                *(float4*)&w1r[0] = *(const float4*)(pm_w1 + 64 + hb);
                *(float4*)&w1r[4] = *(const float4*)(pm_w1 + 64 + hb + 4);
                *(float4*)&w2r[0] = *(const float4*)(pm_w1 + 128 + hb);
                *(float4*)&w2r[4] = *(const float4*)(pm_w1 + 128 + hb + 4);
                *(float4*)&bb[0]  = *(const float4*)(pm_b1 + hb);
                *(float4*)&bb[4]  = *(const float4*)(pm_b1 + hb + 4);
                bf16x8 f;
#pragma unroll
                for (int jj = 0; jj < 8; ++jj) {
                    float v = fmaf(rx, w0[jj], fmaf(ry, w1r[jj], fmaf(rz, w2r[jj], bb[jj])));
                    f[jj] = f2bf_s(fmaxf(v, 0.f));
                }
                h1f[kt] = f;
            }
#pragma unroll
            for (int nt = 0; nt < 4; ++nt) {
                const bf16x8 b0 = *(const bf16x8*)(pw2p + (size_t)((nt * 2 + 0) * 64 + lane) * 8);
                const bf16x8 b1 = *(const bf16x8*)(pw2p + (size_t)((nt * 2 + 1) * 64 + lane) * 8);
                f32x4 acc = {0.f, 0.f, 0.f, 0.f};
                acc = __builtin_amdgcn_mfma_f32_16x16x32_bf16(h1f[0], b0, acc, 0, 0, 0);
                acc = __builtin_amdgcn_mfma_f32_16x16x32_bf16(h1f[1], b1, acc, 0, 0, 0);
                const float bias = pm_b2[16 * nt + nb];
#pragma unroll
                for (int r = 0; r < 4; ++r)
                    s_rel[w][4 * g + r][16 * nt + nb] = (uint16_t)f2bf_s(acc[r] + bias);
            }
        }
        __syncthreads();

#pragma unroll
        for (int pt = 0; pt < 4; ++pt) {
            const int ip   = min(i0 + pt, npts - 1);
            const int nidx = aidx[ip * KNB + nb];
            const uint16_t* kvr = qkvp + (size_t)nidx * QKVW;
            const uint16_t* qr  = qkvp + (size_t)ip * QKVW;

            bf16x8 tf[2];
#pragma unroll
            for (int kt = 0; kt < 2; ++kt) {
                const int cb = 32 * kt + 8 * g;
                const bf16x8 k8 = *(const bf16x8*)(kvr + 64 + cb);
                const bf16x8 q8 = *(const bf16x8*)(qr + cb);
                const bf16x8 r8 = *(const bf16x8*)&s_rel[pt][nb][cb];
                bf16x8 f;
#pragma unroll
                for (int j = 0; j < 8; ++j)
                    f[j] = f2bf_s(bf2f((uint16_t)k8[j]) - bf2f((uint16_t)q8[j]) + bf2f((uint16_t)r8[j]));
                tf[kt] = f;
                if (pt == w) {
                    const bf16x8 v8 = *(const bf16x8*)(kvr + 128 + cb);
                    bf16x8 vf;
#pragma unroll
                    for (int j = 0; j < 8; ++j)
                        vf[j] = f2bf_s(bf2f((uint16_t)v8[j]) + bf2f((uint16_t)r8[j]));
                    *(bf16x8*)&s_vrel[16 * pt + nb][cb] = vf;
                }
            }

            f32x4 acc[4];
#pragma unroll
            for (int m = 0; m < 4; ++m) {
                f32x4 a = {0.f, 0.f, 0.f, 0.f};
                a = __builtin_amdgcn_mfma_f32_16x16x32_bf16(aw1[m][0], tf[0], a, 0, 0, 0);
                a = __builtin_amdgcn_mfma_f32_16x16x32_bf16(aw1[m][1], tf[1], a, 0, 0, 0);
                acc[m] = a;
            }
#pragma unroll
            for (int m = 0; m < 4; ++m) {
                const int hb = 16 * (4 * w + m) + 4 * g;
                const float4 b4 = *(const float4*)(am_b1 + hb);
                const uint32_t lo = (uint32_t)(uint16_t)f2bf_s(fmaxf(acc[m][0] + b4.x, 0.f))
                                  | ((uint32_t)(uint16_t)f2bf_s(fmaxf(acc[m][1] + b4.y, 0.f)) << 16);
                const uint32_t hi = (uint32_t)(uint16_t)f2bf_s(fmaxf(acc[m][2] + b4.z, 0.f))
                                  | ((uint32_t)(uint16_t)f2bf_s(fmaxf(acc[m][3] + b4.w, 0.f)) << 16);
                const int sl = (2 * (4 * w + m) + (g >> 1)) ^ (nb & 7);
                *(uint2*)((char*)&s_h2[16 * pt + nb][0] + sl * 16 + 8 * (g & 1)) = make_uint2(lo, hi);
            }
        }
        __syncthreads();

#pragma unroll
        for (int mt = 0; mt < 4; ++mt) {
            const int ip  = i0 + mt;
            const int ipc = min(ip, npts - 1);

            f32x4 wacc = {0.f, 0.f, 0.f, 0.f};
#pragma unroll
            for (int kt = 0; kt < 8; ++kt) {
                const int sl = (4 * kt + g) ^ (nb & 7);
                const bf16x8 a = *(const bf16x8*)((const char*)&s_h2[16 * mt + nb][0] + sl * 16);
                wacc = __builtin_amdgcn_mfma_f32_16x16x32_bf16(a, aw2[kt], wacc, 0, 0, 0);
            }

            const uchar4 m4 = *(const uchar4*)(mask + (size_t)ipc * KNB + 4 * g);
            const float sc0 = m4.x ? -INFINITY : wacc[0];
            const float sc1 = m4.y ? -INFINITY : wacc[1];
            const float sc2 = m4.z ? -INFINITY : wacc[2];
            const float sc3 = m4.w ? -INFINITY : wacc[3];
            float mx = fmaxf(fmaxf(sc0, sc1), fmaxf(sc2, sc3));
            mx = fmaxf(mx, __shfl_xor(mx, 16));
            mx = fmaxf(mx, __shfl_xor(mx, 32));
            const float e0 = __expf(sc0 - mx), e1 = __expf(sc1 - mx);
            const float e2 = __expf(sc2 - mx), e3 = __expf(sc3 - mx);
            float den = (e0 + e1) + (e2 + e3);

            const int vc = 16 * w + nb;
            const float vr0 = bf2f(s_vrel[16 * mt + 4 * g + 0][vc]);
            const float vr1 = bf2f(s_vrel[16 * mt + 4 * g + 1][vc]);
            const float vr2 = bf2f(s_vrel[16 * mt + 4 * g + 2][vc]);
            const float vr3 = bf2f(s_vrel[16 * mt + 4 * g + 3][vc]);
            float num = e0 * vr0;
            num = fmaf(e1, vr1, num);
            num = fmaf(e2, vr2, num);
            num = fmaf(e3, vr3, num);

            den += __shfl_xor(den, 16); den += __shfl_xor(den, 32);
            num += __shfl_xor(num, 16); num += __shfl_xor(num, 32);
            if (lane < 16 && ip < npts)
                out[(size_t)ip * 64 + vc] = __fdividef(num, den);
        }
    }
}

// ---------------------------------------------------------------------------
extern "C" void kernel_launch(void* const* d_in, const int* in_sizes, int n_in,
                              void* d_out, int out_size, void* d_ws, size_t ws_size,
                              hipStream_t stream) {
    const float*   x     = (const float*)d_in[0];
    const float*   pos   = (const float*)d_in[1];
    const int*     aidx  = (const int*)d_in[2];
    const uint8_t* mask  = (const uint8_t*)d_in[3];
    const float*   wqkv  = (const float*)d_in[4];
    const float*   pm_w1 = (const float*)d_in[5];
    const float*   pm_b1 = (const float*)d_in[6];
    const float*   pm_w2 = (const float*)d_in[7];
    const float*   pm_b2 = (const float*)d_in[8];
    const float*   am_w1 = (const float*)d_in[9];
    const float*   am_b1 = (const float*)d_in[10];
    const float*   am_w2 = (const float*)d_in[11];
    // am_b2 (d_in[12]) cancels over the softmax axis -> unused
    float* out = (float*)d_out;
    const int n = in_sizes[0] / DIM;

    uint8_t* ws = (uint8_t*)d_ws;
    const size_t xw_bytes = (size_t)n * XWW * 2;
    const size_t needed = xw_bytes + 73728 + 32768 + 32768 + 8192 + 1024;

    if (ws_size >= needed) {
        uint16_t* xwp  = (uint16_t*)ws;
        uint16_t* whbp = (uint16_t*)(ws + xw_bytes);
        uint16_t* wprp = (uint16_t*)(ws + xw_bytes + 73728);
        uint16_t* w2p  = (uint16_t*)(ws + xw_bytes + 73728 + 32768);
        uint16_t* pw2p = (uint16_t*)(ws + xw_bytes + 73728 + 32768 + 32768);
        float*    bp   = (float*)   (ws + xw_bytes + 73728 + 32768 + 32768 + 8192);

        pack_kernel<<<290, 256, 0, stream>>>(wqkv, am_w1, am_w2, pm_w2, pm_b2, am_b1,
                                             whbp, wprp, w2p, pw2p, bp);
        xw_kernel<<<(n + 15) / 16, 256, 0, stream>>>(x, whbp, bp, xwp, n);
        ptl_main<<<1024, 256, 0, stream>>>(pos, aidx, mask, pm_w1, pm_b1, pm_b2,
                                           xwp, wprp, w2p, pw2p, out, n);
    } else {
        uint16_t* qkvp = (uint16_t*)ws;
        uint16_t* w1p  = (uint16_t*)(ws + (size_t)n * QKVW * 2);
        uint16_t* w2p  = w1p + 16384;
        uint16_t* pw2p = w2p + 16384;
        const int nqkvb = (n + 15) / 16;
        prep_fb<<<nqkvb + 144, 256, 0, stream>>>(x, wqkv, am_w1, am_w2, pm_w2,
                                                 qkvp, w1p, w2p, pw2p, n, nqkvb);
        ptl_main_fb<<<1024, 256, 0, stream>>>(pos, aidx, mask, pm_w1, pm_b1, pm_b2, am_b1,
                                              qkvp, w1p, w2p, pw2p, out, n);
    }
}

// Round 11
// 205.055 us; speedup vs baseline: 1.3547x; 1.2479x over previous
//
#include <hip/hip_runtime.h>
#include <hip/hip_bf16.h>
#include <math.h>
#include <stdint.h>

#define DIM   64
#define KNB   16
#define QKVW  192

typedef short bf16x8 __attribute__((ext_vector_type(8)));
typedef float f32x4  __attribute__((ext_vector_type(4)));

__device__ __forceinline__ short f2bf_s(float x) {
    return (short)__builtin_bit_cast(unsigned short, __float2bfloat16(x));
}
__device__ __forceinline__ float bf2f(uint16_t u) {
    uint32_t v = ((uint32_t)u) << 16;
    return __builtin_bit_cast(float, v);
}

// ---------------------------------------------------------------------------
// prep: qkv projection (blocks < nqkvb) + weight prepack (remaining blocks).
// qkv -> bf16 [N][192] (q|k|v). Fragment: non-K = lane&15, K = 32kt+8(lane>>4)+j.
// ---------------------------------------------------------------------------
__global__ __launch_bounds__(256) void prep_kernel(
    const float* __restrict__ x, const float* __restrict__ wqkv,
    const float* __restrict__ am_w1, const float* __restrict__ am_w2,
    const float* __restrict__ pm_w2,
    uint16_t* __restrict__ qkvp, uint16_t* __restrict__ w1p,
    uint16_t* __restrict__ w2p, uint16_t* __restrict__ pw2p,
    int n, int nqkvb)
{
    const int tid = threadIdx.x;
    if (blockIdx.x < nqkvb) {
        const int c  = tid & 63;
        const int rq = tid >> 6;
        const int r0 = blockIdx.x * 16;
        __shared__ float s_x[16][64];
#pragma unroll
        for (int t = 0; t < 4; ++t) {
            const int row = r0 + rq + 4 * t;
            s_x[rq + 4 * t][c] = (row < n) ? x[(size_t)row * 64 + c] : 0.f;
        }
        __syncthreads();
        float aq[4] = {0, 0, 0, 0}, ak[4] = {0, 0, 0, 0}, av[4] = {0, 0, 0, 0};
        for (int d = 0; d < 64; ++d) {
            const float w0 = wqkv[d * QKVW + c];
            const float w1 = wqkv[d * QKVW + 64 + c];
            const float w2 = wqkv[d * QKVW + 128 + c];
#pragma unroll
            for (int t = 0; t < 4; ++t) {
                const float xv = s_x[rq + 4 * t][d];
                aq[t] = fmaf(xv, w0, aq[t]);
                ak[t] = fmaf(xv, w1, ak[t]);
                av[t] = fmaf(xv, w2, av[t]);
            }
        }
#pragma unroll
        for (int t = 0; t < 4; ++t) {
            const int row = r0 + rq + 4 * t;
            if (row < n) {
                qkvp[(size_t)row * QKVW + c]       = (uint16_t)f2bf_s(aq[t]);
                qkvp[(size_t)row * QKVW + 64 + c]  = (uint16_t)f2bf_s(ak[t]);
                qkvp[(size_t)row * QKVW + 128 + c] = (uint16_t)f2bf_s(av[t]);
            }
        }
    } else {
        int t = (blockIdx.x - nqkvb) * 256 + tid;
        if (t >= 36864) return;
        int j = t & 7, lane = (t >> 3) & 63, tile = t >> 9;
        int g = lane >> 4, nb = lane & 15;
        if (tile < 32) {
            int mt = tile >> 1, kt = tile & 1;
            w1p[t] = (uint16_t)f2bf_s(am_w1[(32 * kt + 8 * g + j) * 256 + 16 * mt + nb]);
        } else if (tile < 64) {
            int tt = tile - 32;
            int mt = tt >> 3, kt = tt & 7;
            w2p[t - 16384] = (uint16_t)f2bf_s(am_w2[(32 * kt + 8 * g + j) * 64 + 16 * mt + nb]);
        } else {
            int tt = tile - 64;
            int nt = tt >> 1, kt = tt & 1;
            pw2p[t - 32768] = (uint16_t)f2bf_s(pm_w2[(32 * kt + 8 * g + j) * 64 + 16 * nt + nb]);
        }
    }
}

// ---------------------------------------------------------------------------
// Main: round-7 structure (4 points/iter, 4 waves, 2 barriers per 4 points)
// + LDS-scope T14 staging:
//   P3 start : stage_load(next group) — aidx/pos into ~7 regs, k-rows into
//              2 uint4 regs (transient, P3-local)
//   P3 end   : stage_write — ds_write k-tiles XOR-swizzled into s_kv
//   P2       : k read from s_kv (conflict-reduced), NO scattered global loads
//              on the critical path; owner v/q loads issued at P2 top and
//              consumed after the MFMA block.
// q folded into s_rel at P1 (rel' = rel + b - q); vrel = v + rel' + q.
// Hazards (2 barriers): P3 reads s_h2/s_vrel only; next P1 writes s_rel only;
// s_kv written in P3 (readers finished at barrier-2), read in P2 after
// barrier-1' (ds_writes drained by barrier's lgkmcnt, cross-wave visible).
// ---------------------------------------------------------------------------
__global__ __launch_bounds__(256, 2) void ptl_main(
    const float* __restrict__ pos,
    const int* __restrict__ aidx,
    const uint8_t* __restrict__ mask,
    const float* __restrict__ pm_w1,
    const float* __restrict__ pm_b1,
    const float* __restrict__ pm_b2,
    const float* __restrict__ am_b1,
    const uint16_t* __restrict__ qkvp,
    const uint16_t* __restrict__ w1p,
    const uint16_t* __restrict__ w2p,
    const uint16_t* __restrict__ pw2p,
    float* __restrict__ out,
    int npts)
{
    const int tid  = threadIdx.x;
    const int w    = tid >> 6;
    const int lane = tid & 63;
    const int g    = lane >> 4;
    const int nb   = lane & 15;

    __shared__ alignas(16) uint16_t s_rel[4][16][80];   // rel' = rel + b2 - q
    __shared__ alignas(16) uint16_t s_vrel[64][80];     // v + rel
    __shared__ alignas(16) uint16_t s_h2[64][256];      // slot-XOR swizzled
    __shared__ alignas(16) uint16_t s_kv[4][16][64];    // staged k, chunk^row swz

    // register-resident weights (64 VGPR)
    bf16x8 aw1[4][2], aw2[8];
#pragma unroll
    for (int m = 0; m < 4; ++m)
#pragma unroll
        for (int kt = 0; kt < 2; ++kt)
            aw1[m][kt] = *(const bf16x8*)(w1p + (size_t)(((4 * w + m) * 2 + kt) * 64 + lane) * 8);
#pragma unroll
    for (int kt = 0; kt < 8; ++kt)
        aw2[kt] = *(const bf16x8*)(w2p + (size_t)((w * 8 + kt) * 64 + lane) * 8);

    const int ngroups = (npts + 3) >> 2;
    const int srow = lane >> 3;       // staging row (0..7), +8 for second tile
    const int schk = lane & 7;        // staging logical chunk
    const int spc  = schk ^ (srow & 7);  // physical chunk (swizzle)

    // ---- cross-iteration prefetch state ----
    int   pnw;                         // aidx of (next point of this wave, nb)
    float cx, cy, cz, prx, pry, prz;   // center / neighbor pos
    uint4 stk0, stk1;                  // staged k rows (P3-local live range)

    auto stage_load = [&](int gbn) {
        const int gcl = min(gbn, ngroups - 1);
        const int ipn = min(gcl * 4 + w, npts - 1);
        pnw = aidx[ipn * KNB + nb];
        cx = pos[3 * ipn]; cy = pos[3 * ipn + 1]; cz = pos[3 * ipn + 2];
        prx = pos[3 * pnw]; pry = pos[3 * pnw + 1]; prz = pos[3 * pnw + 2];
        const int rA = aidx[ipn * KNB + srow];
        const int rB = aidx[ipn * KNB + 8 + srow];
        stk0 = *(const uint4*)(qkvp + (size_t)rA * QKVW + 64 + schk * 8);
        stk1 = *(const uint4*)(qkvp + (size_t)rB * QKVW + 64 + schk * 8);
    };
    auto stage_write = [&]() {
        *(uint4*)&s_kv[w][srow][spc * 8]     = stk0;
        *(uint4*)&s_kv[w][8 + srow][spc * 8] = stk1;
    };

    stage_load(blockIdx.x);
    stage_write();

    for (int gb = blockIdx.x; gb < ngroups; gb += gridDim.x) {
        const int i0 = gb * 4;

        // ================= P1: rel' for point i0+w (prefetched pos) ==========
        {
            const int ipw = min(i0 + w, npts - 1);
            const float rx = prx - cx, ry = pry - cy, rz = prz - cz;

            bf16x8 h1f[2];
#pragma unroll
            for (int kt = 0; kt < 2; ++kt) {
                const int hb = 32 * kt + 8 * g;
                float w0[8], w1r[8], w2r[8], bb[8];
                *(float4*)&w0[0]  = *(const float4*)(pm_w1 + hb);
                *(float4*)&w0[4]  = *(const float4*)(pm_w1 + hb + 4);
                *(float4*)&w1r[0] = *(const float4*)(pm_w1 + 64 + hb);
                *(float4*)&w1r[4] = *(const float4*)(pm_w1 + 64 + hb + 4);
                *(float4*)&w2r[0] = *(const float4*)(pm_w1 + 128 + hb);
                *(float4*)&w2r[4] = *(const float4*)(pm_w1 + 128 + hb + 4);
                *(float4*)&bb[0]  = *(const float4*)(pm_b1 + hb);
                *(float4*)&bb[4]  = *(const float4*)(pm_b1 + hb + 4);
                bf16x8 f;
#pragma unroll
                for (int jj = 0; jj < 8; ++jj) {
                    float v = fmaf(rx, w0[jj], fmaf(ry, w1r[jj], fmaf(rz, w2r[jj], bb[jj])));
                    f[jj] = f2bf_s(fmaxf(v, 0.f));
                }
                h1f[kt] = f;
            }
#pragma unroll
            for (int nt = 0; nt < 4; ++nt) {
                const bf16x8 b0 = *(const bf16x8*)(pw2p + (size_t)((nt * 2 + 0) * 64 + lane) * 8);
                const bf16x8 b1 = *(const bf16x8*)(pw2p + (size_t)((nt * 2 + 1) * 64 + lane) * 8);
                f32x4 acc = {0.f, 0.f, 0.f, 0.f};
                acc = __builtin_amdgcn_mfma_f32_16x16x32_bf16(h1f[0], b0, acc, 0, 0, 0);
                acc = __builtin_amdgcn_mfma_f32_16x16x32_bf16(h1f[1], b1, acc, 0, 0, 0);
                const int ch = 16 * nt + nb;
                const float bias = pm_b2[ch];
                const float qv = bf2f(qkvp[(size_t)ipw * QKVW + ch]);  // fold -q
#pragma unroll
                for (int r = 0; r < 4; ++r)
                    s_rel[w][4 * g + r][ch] = (uint16_t)f2bf_s(acc[r] + bias - qv);
            }
        }
        __syncthreads();   // barrier-1 (also drains prev P3's ds_writes)

        // ================= P2: h2 stripe for all 64 pairs ====================
        {
            // early-issue owner loads (consumed after the MFMA block)
            const int ipo = min(i0 + w, npts - 1);
            const bf16x8 v8a = *(const bf16x8*)(qkvp + (size_t)pnw * 0 +  // dummy to keep pnw? no
                                                (size_t)aidx[ipo * KNB + nb] * QKVW + 128 + 8 * g);
            const bf16x8 v8b = *(const bf16x8*)(qkvp + (size_t)aidx[ipo * KNB + nb] * QKVW + 160 + 8 * g);
            const bf16x8 q8a = *(const bf16x8*)(qkvp + (size_t)ipo * QKVW + 8 * g);
            const bf16x8 q8b = *(const bf16x8*)(qkvp + (size_t)ipo * QKVW + 32 + 8 * g);

#pragma unroll
            for (int pt = 0; pt < 4; ++pt) {
                const int pc0 = g ^ (nb & 7);
                const int pc1 = (4 + g) ^ (nb & 7);
                const bf16x8 k0 = *(const bf16x8*)&s_kv[pt][nb][pc0 * 8];
                const bf16x8 k1 = *(const bf16x8*)&s_kv[pt][nb][pc1 * 8];
                const bf16x8 r0 = *(const bf16x8*)&s_rel[pt][nb][8 * g];
                const bf16x8 r1 = *(const bf16x8*)&s_rel[pt][nb][32 + 8 * g];
                bf16x8 tf0, tf1;
#pragma unroll
                for (int j = 0; j < 8; ++j) {
                    tf0[j] = f2bf_s(bf2f((uint16_t)k0[j]) + bf2f((uint16_t)r0[j]));
                    tf1[j] = f2bf_s(bf2f((uint16_t)k1[j]) + bf2f((uint16_t)r1[j]));
                }

                f32x4 hacc[4];
#pragma unroll
                for (int m = 0; m < 4; ++m) {
                    f32x4 a = {0.f, 0.f, 0.f, 0.f};
                    a = __builtin_amdgcn_mfma_f32_16x16x32_bf16(aw1[m][0], tf0, a, 0, 0, 0);
                    a = __builtin_amdgcn_mfma_f32_16x16x32_bf16(aw1[m][1], tf1, a, 0, 0, 0);
                    hacc[m] = a;
                }
#pragma unroll
                for (int m = 0; m < 4; ++m) {
                    const int hb = 16 * (4 * w + m) + 4 * g;
                    const float4 b4 = *(const float4*)(am_b1 + hb);
                    const uint32_t lo = (uint32_t)(uint16_t)f2bf_s(fmaxf(hacc[m][0] + b4.x, 0.f))
                                      | ((uint32_t)(uint16_t)f2bf_s(fmaxf(hacc[m][1] + b4.y, 0.f)) << 16);
                    const uint32_t hi = (uint32_t)(uint16_t)f2bf_s(fmaxf(hacc[m][2] + b4.z, 0.f))
                                      | ((uint32_t)(uint16_t)f2bf_s(fmaxf(hacc[m][3] + b4.w, 0.f)) << 16);
                    const int sl = (2 * (4 * w + m) + (g >> 1)) ^ (nb & 7);
                    *(uint2*)((char*)&s_h2[16 * pt + nb][0] + sl * 16 + 8 * (g & 1)) = make_uint2(lo, hi);
                }
            }

            // vrel = v + rel' + q  (each wave owns pt = w)
            {
                const bf16x8 r0 = *(const bf16x8*)&s_rel[w][nb][8 * g];
                const bf16x8 r1 = *(const bf16x8*)&s_rel[w][nb][32 + 8 * g];
                bf16x8 va, vb;
#pragma unroll
                for (int j = 0; j < 8; ++j) {
                    va[j] = f2bf_s(bf2f((uint16_t)v8a[j]) + bf2f((uint16_t)r0[j]) + bf2f((uint16_t)q8a[j]));
                    vb[j] = f2bf_s(bf2f((uint16_t)v8b[j]) + bf2f((uint16_t)r1[j]) + bf2f((uint16_t)q8b[j]));
                }
                *(bf16x8*)&s_vrel[16 * w + nb][8 * g]      = va;
                *(bf16x8*)&s_vrel[16 * w + nb][32 + 8 * g] = vb;
            }
        }
        __syncthreads();   // barrier-2

        // ================= P3: stage next group, scores+softmax+agg ==========
        stage_load(gb + gridDim.x);

#pragma unroll
        for (int mt = 0; mt < 4; ++mt) {
            const int ip  = i0 + mt;
            const int ipc = min(ip, npts - 1);

            f32x4 wacc = {0.f, 0.f, 0.f, 0.f};
#pragma unroll
            for (int kt = 0; kt < 8; ++kt) {
                const int sl = (4 * kt + g) ^ (nb & 7);
                const bf16x8 a = *(const bf16x8*)((const char*)&s_h2[16 * mt + nb][0] + sl * 16);
                wacc = __builtin_amdgcn_mfma_f32_16x16x32_bf16(a, aw2[kt], wacc, 0, 0, 0);
            }

            const uchar4 m4 = *(const uchar4*)(mask + (size_t)ipc * KNB + 4 * g);
            const float sc0 = m4.x ? -INFINITY : wacc[0];
            const float sc1 = m4.y ? -INFINITY : wacc[1];
            const float sc2 = m4.z ? -INFINITY : wacc[2];
            const float sc3 = m4.w ? -INFINITY : wacc[3];
            float mx = fmaxf(fmaxf(sc0, sc1), fmaxf(sc2, sc3));
            mx = fmaxf(mx, __shfl_xor(mx, 16));
            mx = fmaxf(mx, __shfl_xor(mx, 32));
            const float e0 = __expf(sc0 - mx), e1 = __expf(sc1 - mx);
            const float e2 = __expf(sc2 - mx), e3 = __expf(sc3 - mx);
            float den = (e0 + e1) + (e2 + e3);

            const int vc = 16 * w + nb;
            const float vr0 = bf2f(s_vrel[16 * mt + 4 * g + 0][vc]);
            const float vr1 = bf2f(s_vrel[16 * mt + 4 * g + 1][vc]);
            const float vr2 = bf2f(s_vrel[16 * mt + 4 * g + 2][vc]);
            const float vr3 = bf2f(s_vrel[16 * mt + 4 * g + 3][vc]);
            float num = e0 * vr0;
            num = fmaf(e1, vr1, num);
            num = fmaf(e2, vr2, num);
            num = fmaf(e3, vr3, num);

            den += __shfl_xor(den, 16); den += __shfl_xor(den, 32);
            num += __shfl_xor(num, 16); num += __shfl_xor(num, 32);
            if (lane < 16 && ip < npts)
                out[(size_t)ip * 64 + vc] = __fdividef(num, den);
        }

        stage_write();   // ds_write staged k; drained/visible at barrier-1'
        // no third barrier needed (see header comment)
    }
}

// ---------------------------------------------------------------------------
extern "C" void kernel_launch(void* const* d_in, const int* in_sizes, int n_in,
                              void* d_out, int out_size, void* d_ws, size_t ws_size,
                              hipStream_t stream) {
    const float*   x     = (const float*)d_in[0];
    const float*   pos   = (const float*)d_in[1];
    const int*     aidx  = (const int*)d_in[2];
    const uint8_t* mask  = (const uint8_t*)d_in[3];
    const float*   wqkv  = (const float*)d_in[4];
    const float*   pm_w1 = (const float*)d_in[5];
    const float*   pm_b1 = (const float*)d_in[6];
    const float*   pm_w2 = (const float*)d_in[7];
    const float*   pm_b2 = (const float*)d_in[8];
    const float*   am_w1 = (const float*)d_in[9];
    const float*   am_b1 = (const float*)d_in[10];
    const float*   am_w2 = (const float*)d_in[11];
    // am_b2 (d_in[12]) is constant over the softmax axis -> cancels, unused
    float* out = (float*)d_out;
    const int n = in_sizes[0] / DIM;

    uint8_t* ws = (uint8_t*)d_ws;
    uint16_t* qkvp = (uint16_t*)ws;                               // n*192 bf16
    uint16_t* w1p  = (uint16_t*)(ws + (size_t)n * QKVW * 2);      // 16384 bf16
    uint16_t* w2p  = w1p + 16384;                                 // 16384 bf16
    uint16_t* pw2p = w2p + 16384;                                 // 4096 bf16

    const int nqkvb = (n + 15) / 16;
    prep_kernel<<<nqkvb + 144, 256, 0, stream>>>(x, wqkv, am_w1, am_w2, pm_w2,
                                                 qkvp, w1p, w2p, pw2p, n, nqkvb);
    ptl_main<<<512, 256, 0, stream>>>(pos, aidx, mask, pm_w1, pm_b1, pm_b2, am_b1,
                                      qkvp, w1p, w2p, pw2p, out, n);
}